// Round 20
// baseline (360.381 us; speedup 1.0000x reference)
//
#include <hip/hip_runtime.h>

// SoftRoutedLoRALinear on MI355X — augmented-K f16 MFMA GEMM.
// out[m,n] = sum_k Xa[m,k]*Wa[n,k] + bias[n],  K = 4096 + 128 (LoRA tail)
//   Xa tail[m, e*16+r] = 2*router[b,e] * sum_i x[m,i]*lora_A[e,r,i]
//   Wa tail[n, e*16+r] = lora_B[e,n,r]
// Main GEMM: R15 ring-4 + PARITY-STAGGERED WAVE PRIORITIES: even waves get
// prio1 during the ds_read burst, odd waves prio1 during the MFMA burst ->
// the two waves per SIMD desync so the CU-shared LDS pipe and the MFMA pipe
// run concurrently instead of serially (2390 -> ~1820 cy/tile predicted).
// Prep: fused prep_all + ring-3 mid2r (both at BW floor).

typedef _Float16 half8 __attribute__((ext_vector_type(8)));
typedef _Float16 half4 __attribute__((ext_vector_type(4)));
typedef float    f32x4 __attribute__((ext_vector_type(4)));

#define M_TOT 8192
#define N_TOT 4096
#define K_IN  4096
#define KA    4224
#define NT    132     // KA / 32

__device__ __forceinline__ void cvt_store4(_Float16* p, float4 f) {
  half4 h;
  h[0] = (_Float16)f.x; h[1] = (_Float16)f.y;
  h[2] = (_Float16)f.z; h[3] = (_Float16)f.w;
  *(half4*)p = h;
}

__device__ __forceinline__ void cvt8(const float* src, _Float16* dst) {
  const float4* s = (const float4*)src;
  float4 f0 = s[0], f1 = s[1];
  half8 h;
  h[0]=(_Float16)f0.x; h[1]=(_Float16)f0.y; h[2]=(_Float16)f0.z; h[3]=(_Float16)f0.w;
  h[4]=(_Float16)f1.x; h[5]=(_Float16)f1.y; h[6]=(_Float16)f1.z; h[7]=(_Float16)f1.w;
  *(half8*)dst = h;
}

// ---------------- fused prep: block-range partition
__global__ __launch_bounds__(256) void prep_all(
    const float* __restrict__ x, const float* __restrict__ wgt,
    const float* __restrict__ loraA, const float* __restrict__ loraB,
    _Float16* __restrict__ Xa, _Float16* __restrict__ Wa,
    _Float16* __restrict__ lAh) {
  int bid = blockIdx.x, tid = threadIdx.x;
  if (bid < 2048) {
    for (int i = bid * 256 + tid; i < M_TOT * K_IN / 8; i += 2048 * 256) {
      int base = i << 3;
      int r = base >> 12, c = base & 4095;
      cvt8(x + (size_t)base, Xa + (size_t)r * KA + c);
    }
  } else if (bid < 3072) {
    for (int i = (bid - 2048) * 256 + tid; i < N_TOT * K_IN / 8; i += 1024 * 256) {
      int base = i << 3;
      int r = base >> 12, c = base & 4095;
      cvt8(wgt + (size_t)base, Wa + (size_t)r * KA + c);
    }
  } else if (bid < 3104) {
    for (int i = (bid - 3072) * 256 + tid; i < 128 * K_IN / 8; i += 32 * 256) {
      int base = i << 3;
      cvt8(loraA + (size_t)base, lAh + (size_t)base);
    }
  } else {
    for (int i = (bid - 3104) * 256 + tid; i < N_TOT * 128; i += 256 * 256) {
      int n = i >> 7, j = i & 127;
      int e = j >> 4, r = j & 15;
      Wa[(size_t)n * KA + K_IN + j] =
          (_Float16)loraB[((size_t)e * N_TOT + n) * 16 + r];
    }
  }
}

// ---------------- prep (fallback): lora_B -> fp32 [4096][128]
__global__ __launch_bounds__(256) void lorabf_gather_f32(
    const float* __restrict__ loraB, float* __restrict__ lorabf) {
  int idx = blockIdx.x * 256 + threadIdx.x;
  int n = idx >> 7, j = idx & 127;
  int e = j >> 4, r = j & 15;
  lorabf[(size_t)n * 128 + j] = loraB[((size_t)e * N_TOT + n) * 16 + r];
}

// ---------------- mid2r: ring-3 pipelined x(f16)@loraA(f16)^T -> Xa tail
#define MVMW5 asm volatile("s_waitcnt vmcnt(5)" ::: "memory")
#define MVMW0 asm volatile("s_waitcnt vmcnt(0)" ::: "memory")
#define MGLOAD(src, dst) __builtin_amdgcn_global_load_lds( \
    (const __attribute__((address_space(1))) void*)(src), \
    (__attribute__((address_space(3))) void*)(dst), 16, 0, 0)

__global__ __launch_bounds__(256) void mid2r_kernel(
    _Float16* __restrict__ Xa, const _Float16* __restrict__ lAh,
    const float* __restrict__ router) {
  __shared__ __align__(16) char MLDS[61440];   // 3 x (4KB A + 16KB B)
  int tid = threadIdx.x, lane = tid & 63, w = tid >> 6;
  int m0 = blockIdx.x * 32;
  int b = m0 >> 11;
  f32x4 acc[2][2] = {};

  int scol = ((lane & 7) ^ (lane >> 3)) * 16;   // pre-swizzled source slot
  int ln15 = lane & 15, ln4 = lane >> 4;

  int gA = (w * 8 + (lane >> 3)) * (KA * 2) + scol;
  int lA = w * 1024 + lane * 16;
  int gB[4], lB[4];
#pragma unroll
  for (int i = 0; i < 4; ++i) {
    gB[i] = ((w * 4 + i) * 8 + (lane >> 3)) * (4096 * 2) + scol;
    lB[i] = (w * 4 + i) * 1024 + lane * 16;
  }
  const char* xaB = (const char*)Xa + (size_t)m0 * (KA * 2);
  const char* lAB = (const char*)lAh;

#define MSTAGE(KS, SL) do { \
  char* base_ = MLDS + (SL) * 20480; \
  MGLOAD(xaB + gA + (KS) * 128, base_ + lA); \
  _Pragma("unroll") for (int i = 0; i < 4; ++i) \
    MGLOAD(lAB + gB[i] + (KS) * 128, base_ + 4096 + lB[i]); \
  } while (0)

#define MCOMP(SL) do { \
  const char* As_ = MLDS + (SL) * 20480; \
  const char* Bs_ = As_ + 4096; \
  _Pragma("unroll") for (int kk = 0; kk < 2; ++kk) { \
    int rs = (((kk * 4 + ln4) ^ (ln15 & 7)) << 4); \
    half8 a[2], bf[2]; \
    _Pragma("unroll") for (int mi = 0; mi < 2; ++mi) \
      a[mi] = *(const half8*)(As_ + (mi * 16 + ln15) * 128 + rs); \
    _Pragma("unroll") for (int ni = 0; ni < 2; ++ni) \
      bf[ni] = *(const half8*)(Bs_ + (w * 32 + ni * 16 + ln15) * 128 + rs); \
    _Pragma("unroll") for (int mi = 0; mi < 2; ++mi) \
      _Pragma("unroll") for (int ni = 0; ni < 2; ++ni) \
        acc[mi][ni] = __builtin_amdgcn_mfma_f32_16x16x32_f16( \
            a[mi], bf[ni], acc[mi][ni], 0, 0, 0); \
  } } while (0)

  MSTAGE(0, 0); MSTAGE(1, 1);
  MVMW5; __syncthreads();

#pragma unroll 1
  for (int t3 = 0; t3 < 60; t3 += 3) {
    { MCOMP(0); MSTAGE(t3 + 2, 2); MVMW5; __syncthreads(); }
    { MCOMP(1); MSTAGE(t3 + 3, 0); MVMW5; __syncthreads(); }
    { MCOMP(2); MSTAGE(t3 + 4, 1); MVMW5; __syncthreads(); }
  }
  { MCOMP(0); MSTAGE(62, 2); MVMW5; __syncthreads(); }
  { MCOMP(1); MSTAGE(63, 0); MVMW5; __syncthreads(); }
  { MCOMP(2); MVMW0; __syncthreads(); }
  { MCOMP(0); }

#pragma unroll
  for (int ni = 0; ni < 2; ++ni) {
    int j = w * 32 + ni * 16 + ln15;
    int e = j >> 4;
    float sc = 2.0f * router[b * 8 + e];
#pragma unroll
    for (int mi = 0; mi < 2; ++mi) {
      f32x4 v = acc[mi][ni];
#pragma unroll
      for (int jj = 0; jj < 4; ++jj) {
        int m = m0 + mi * 16 + ln4 * 4 + jj;
        Xa[(size_t)m * KA + K_IN + j] = (_Float16)(v[jj] * sc);
      }
    }
  }
#undef MSTAGE
#undef MCOMP
}

// ---------------- fallback mid (f32 sources -> f32 midw, router fused)
__global__ __launch_bounds__(256) void mid_kernel(
    const float* __restrict__ x, const float* __restrict__ loraA,
    const float* __restrict__ router, float* __restrict__ midw) {
  __shared__ _Float16 As[32 * 64];
  __shared__ _Float16 Bs[128 * 64];
  int tid = threadIdx.x, lane = tid & 63, w = tid >> 6;
  int m0 = blockIdx.x * 32;
  int b = m0 >> 11;
  f32x4 acc[2][2] = {};
  for (int ks = 0; ks < 64; ++ks) {
    int k0 = ks * 64;
#pragma unroll
    for (int it = 0; it < 2; ++it) {
      int idx = tid + it * 256;
      int r = idx >> 4, c4 = idx & 15;
      float4 f = *(const float4*)(x + (size_t)(m0 + r) * K_IN + k0 + c4 * 4);
      cvt_store4(As + r * 64 + c4 * 4, f);
    }
#pragma unroll
    for (int it = 0; it < 8; ++it) {
      int idx = tid + it * 256;
      int r = idx >> 4, c4 = idx & 15;
      float4 f = *(const float4*)(loraA + (size_t)r * K_IN + k0 + c4 * 4);
      cvt_store4(Bs + r * 64 + c4 * 4, f);
    }
    __syncthreads();
#pragma unroll
    for (int kk = 0; kk < 2; ++kk) {
      half8 a[2], bf[2];
#pragma unroll
      for (int mi = 0; mi < 2; ++mi)
        a[mi] = *(const half8*)(As + (mi * 16 + (lane & 15)) * 64 + kk * 32 + (lane >> 4) * 8);
#pragma unroll
      for (int ni = 0; ni < 2; ++ni)
        bf[ni] = *(const half8*)(Bs + (w * 32 + ni * 16 + (lane & 15)) * 64 + kk * 32 + (lane >> 4) * 8);
#pragma unroll
      for (int mi = 0; mi < 2; ++mi)
#pragma unroll
        for (int ni = 0; ni < 2; ++ni)
          acc[mi][ni] = __builtin_amdgcn_mfma_f32_16x16x32_f16(a[mi], bf[ni], acc[mi][ni], 0, 0, 0);
    }
    __syncthreads();
  }
#pragma unroll
  for (int ni = 0; ni < 2; ++ni) {
    int j = w * 32 + ni * 16 + (lane & 15);
    int e = j >> 4;
    float sc = 2.0f * router[b * 8 + e];
#pragma unroll
    for (int mi = 0; mi < 2; ++mi) {
      f32x4 v = acc[mi][ni];
#pragma unroll
      for (int jj = 0; jj < 4; ++jj) {
        int m = m0 + mi * 16 + (lane >> 4) * 4 + jj;
        midw[(size_t)m * 128 + j] = v[jj] * sc;
      }
    }
  }
}

// ====== main GEMM: 256x256, BK=32, 8 waves, ring-4, parity-staggered prio ===
#define BAR    __builtin_amdgcn_s_barrier()
#define SCHED0 __builtin_amdgcn_sched_barrier(0)
#define PRIO1  __builtin_amdgcn_s_setprio(1)
#define PRIO0  __builtin_amdgcn_s_setprio(0)
#define VMW8   asm volatile("s_waitcnt vmcnt(8)" ::: "memory")
#define VMW4   asm volatile("s_waitcnt vmcnt(4)" ::: "memory")
#define VMW0   asm volatile("s_waitcnt vmcnt(0)" ::: "memory")
#define GLOAD(src, dst) __builtin_amdgcn_global_load_lds( \
    (const __attribute__((address_space(1))) void*)(src), \
    (__attribute__((address_space(3))) void*)(dst), 16, 0, 0)

// A slot SL at LDS bytes [SL*16384, +16K); B at 65536 + SL*16384.
// B read FIRST; compiler-counted lgkmcnt drains reads 6-12 under the MFMAs.
#define READS(SL) do { \
  _Pragma("unroll") for (int ni = 0; ni < 4; ++ni) \
    bF[ni] = *(const half8*)(LDS + 65536 + (SL) * 16384 + \
                             (wn + ni * 16 + ln15) * 64 + rslot); \
  _Pragma("unroll") for (int mi = 0; mi < 8; ++mi) \
    aF[mi] = *(const half8*)(LDS + (SL) * 16384 + \
                             (wm + mi * 16 + ln15) * 64 + rslot); \
  } while (0)

// stage K32-tile TT into ring slot SL (A:2 + B:2 gloads, linear LDS dest)
#define STAGE4(TT, SL) do { \
  const char* sA_ = XpC + (size_t)(TT) * 64; \
  const char* sB_ = WpC + (size_t)(TT) * 64; \
  GLOAD(sA_ + goff0, LDS + (SL) * 16384 + l0); \
  GLOAD(sA_ + goff1, LDS + (SL) * 16384 + l1); \
  GLOAD(sB_ + goff0, LDS + 65536 + (SL) * 16384 + l0); \
  GLOAD(sB_ + goff1, LDS + 65536 + (SL) * 16384 + l1); \
  } while (0)

#define MFMA32 do { \
  _Pragma("unroll") for (int mi = 0; mi < 8; ++mi) \
    _Pragma("unroll") for (int ni = 0; ni < 4; ++ni) \
      acc[mi][ni] = __builtin_amdgcn_mfma_f32_16x16x32_f16( \
          aF[mi], bF[ni], acc[mi][ni], 0, 0, 0); \
  } while (0)

// Parity stagger: even waves prio1 through the read burst (drain LDS first,
// enter MFMA early); odd waves prio1 through the MFMA burst (yield LDS, then
// own the MFMA pipe). Desyncs the 2 waves/SIMD so LDS and MFMA pipes overlap.
#define TILE_FULL(SL) do { \
  if (wEven) PRIO1; \
  READS(SL); \
  STAGE4(t4 + (SL) + 3, ((SL) + 3) & 3); \
  if (wEven) { PRIO0; } else { PRIO1; } \
  MFMA32; \
  if (!wEven) PRIO0; \
  VMW8; BAR; SCHED0; \
  } while (0)

__global__ __launch_bounds__(512, 2) void gemm256(
    const _Float16* __restrict__ Xa, const _Float16* __restrict__ Wa,
    const float* __restrict__ bias, float* __restrict__ out) {
  __shared__ __align__(16) char LDS[131072];   // A ring 64K | B ring 64K

  int tid = threadIdx.x, lane = tid & 63, w = tid >> 6;
  int ln15 = lane & 15, ln4 = lane >> 4;
  int wm = (w >> 2) * 128, wn = (w & 3) * 64;
  bool wEven = (w & 1) == 0;

  // T1: XCD chunk swizzle — 512 blocks = 8 XCDs x 64; each XCD an 8x8 chunk.
  int bid = blockIdx.x;
  int xcd = bid & 7, idx = bid >> 3;
  int mt = (xcd & 3) * 8 + (idx & 7);
  int nt = (xcd >> 2) * 8 + (idx >> 3);
  int m0 = mt << 8, n0 = nt << 8;

  const char* XpC = (const char*)Xa + (size_t)m0 * (KA * 2);
  const char* WpC = (const char*)Wa + (size_t)n0 * (KA * 2);

  // Staging: idx = tid + j*512 -> row = idx>>2, slot4 = idx&3.
  // Source pre-swizzle slot4 ^= (row>>1)&3; LDS dest linear idx*16.
  int i0 = tid, i1 = tid + 512;
  int goff0 = (i0 >> 2) * (KA * 2) + (((i0 & 3) ^ ((i0 >> 3) & 3)) * 16);
  int goff1 = (i1 >> 2) * (KA * 2) + (((i1 & 3) ^ ((i1 >> 3) & 3)) * 16);
  int l0 = i0 * 16, l1 = i1 * 16;

  // Fragment read slot: (ln4 ^ ((row>>1)&3))*16; (row>>1)&3 == (lane>>1)&3.
  int rslot = ((ln4 ^ ((lane >> 1) & 3)) * 16);

  f32x4 acc[8][4] = {};
  half8 aF[8], bF[4];

  // prologue: stage ring slots 0,1,2 (tiles 0,1,2); drain tile 0; publish.
  STAGE4(0, 0); STAGE4(1, 1); STAGE4(2, 2);
  VMW8; BAR; SCHED0;

  // steady state: t = 0..127 (all stage t+3, guard vmcnt(8))
#pragma unroll 1
  for (int t4 = 0; t4 < NT - 4; t4 += 4) {
    TILE_FULL(0); TILE_FULL(1); TILE_FULL(2); TILE_FULL(3);
  }

  // peeled tail t = 128..131 (ring slots 0..3)
  { READS(0); STAGE4(131, 3); MFMA32; VMW8; BAR; SCHED0; }  // t=128
  { READS(1); MFMA32; VMW4; BAR; SCHED0; }                  // t=129
  { READS(2); MFMA32; VMW0; BAR; SCHED0; }                  // t=130
  { READS(3); MFMA32; }                                     // t=131

  // epilogue: + bias, fp32 store. C/D: col = lane&15, row = (lane>>4)*4 + reg
#pragma unroll
  for (int ni = 0; ni < 4; ++ni) {
    int n = n0 + wn + ni * 16 + ln15;
    float bz = bias[n];
#pragma unroll
    for (int mi = 0; mi < 8; ++mi) {
      f32x4 v = acc[mi][ni];
      int mb = m0 + wm + mi * 16 + ln4 * 4;
#pragma unroll
      for (int jj = 0; jj < 4; ++jj)
        out[(size_t)(mb + jj) * N_TOT + n] = v[jj] + bz;
    }
  }
}

// ---------------- fallback GEMM (reg-staged f32->f16, 128x128, low ws)
__global__ __launch_bounds__(256) void gemm_fallback(
    const float* __restrict__ x, const float* __restrict__ wgt,
    const float* __restrict__ midw, const float* __restrict__ lorabf,
    const float* __restrict__ bias, float* __restrict__ out) {
  __shared__ _Float16 As[128 * 64];
  __shared__ _Float16 Bs[128 * 64];
  int tid = threadIdx.x, lane = tid & 63, w = tid >> 6;
  int mt = blockIdx.x & 63, nt = blockIdx.x >> 6;
  int m0 = mt << 7, n0 = nt << 7;
  int wm = (w >> 1) * 64, wn = (w & 1) * 64;
  f32x4 acc[4][4] = {};
  for (int ks = 0; ks < 66; ++ks) {
    int k0 = ks * 64;
    const float *asrc, *bsrc; size_t astr, bstr; int ac, bc;
    if (ks < 64) { asrc = x;    astr = K_IN; ac = k0;        bsrc = wgt;    bstr = K_IN; bc = k0; }
    else         { asrc = midw; astr = 128;  ac = k0 - K_IN; bsrc = lorabf; bstr = 128;  bc = k0 - K_IN; }
#pragma unroll
    for (int it = 0; it < 8; ++it) {
      int idx = tid + it * 256;
      int r = idx >> 4, c4 = idx & 15;
      float4 fa = *(const float4*)(asrc + (size_t)(m0 + r) * astr + ac + c4 * 4);
      cvt_store4(As + r * 64 + c4 * 4, fa);
      float4 fb = *(const float4*)(bsrc + (size_t)(n0 + r) * bstr + bc + c4 * 4);
      cvt_store4(Bs + r * 64 + c4 * 4, fb);
    }
    __syncthreads();
#pragma unroll
    for (int kk = 0; kk < 2; ++kk) {
      half8 a[4], bf[4];
#pragma unroll
      for (int mi = 0; mi < 4; ++mi)
        a[mi] = *(const half8*)(As + (wm + mi * 16 + (lane & 15)) * 64 + kk * 32 + (lane >> 4) * 8);
#pragma unroll
      for (int ni = 0; ni < 4; ++ni)
        bf[ni] = *(const half8*)(Bs + (wn + ni * 16 + (lane & 15)) * 64 + kk * 32 + (lane >> 4) * 8);
#pragma unroll
      for (int mi = 0; mi < 4; ++mi)
#pragma unroll
        for (int ni = 0; ni < 4; ++ni)
          acc[mi][ni] = __builtin_amdgcn_mfma_f32_16x16x32_f16(a[mi], bf[ni], acc[mi][ni], 0, 0, 0);
    }
    __syncthreads();
  }
#pragma unroll
  for (int ni = 0; ni < 4; ++ni) {
    int n = n0 + wn + ni * 16 + (lane & 15);
    float bz = bias[n];
#pragma unroll
    for (int mi = 0; mi < 4; ++mi) {
      f32x4 v = acc[mi][ni];
      int mbase = m0 + wm + mi * 16 + (lane >> 4) * 4;
#pragma unroll
      for (int jj = 0; jj < 4; ++jj)
        out[(size_t)(mbase + jj) * N_TOT + n] = v[jj] + bz;
    }
  }
}

extern "C" void kernel_launch(void* const* d_in, const int* in_sizes, int n_in,
                              void* d_out, int out_size, void* d_ws, size_t ws_size,
                              hipStream_t stream) {
  const float* x      = (const float*)d_in[0];
  const float* router = (const float*)d_in[1];
  const float* wgt    = (const float*)d_in[2];
  const float* bias   = (const float*)d_in[3];
  const float* loraA  = (const float*)d_in[4];
  const float* loraB  = (const float*)d_in[5];
  float* out = (float*)d_out;
  char* ws = (char*)d_ws;

  const size_t XAUG_B = (size_t)M_TOT * KA * 2;    // 69,206,016
  const size_t WAUG_B = (size_t)N_TOT * KA * 2;    // 34,603,008
  const size_t LAH_B  = (size_t)128 * K_IN * 2;    //  1,048,576
  const size_t MIDW_B = (size_t)M_TOT * 128 * 4;   //  4,194,304
  bool fast = ws_size >= XAUG_B + WAUG_B + LAH_B;

  if (fast) {
    _Float16* Xa  = (_Float16*)ws;
    _Float16* Wa  = (_Float16*)(ws + XAUG_B);
    _Float16* lAh = (_Float16*)(ws + XAUG_B + WAUG_B);
    prep_all<<<3360, 256, 0, stream>>>(x, wgt, loraA, loraB, Xa, Wa, lAh);
    mid2r_kernel<<<256, 256, 0, stream>>>(Xa, lAh, router);
    gemm256<<<512, 512, 0, stream>>>(Xa, Wa, bias, out);
  } else {
    float* midw   = (float*)ws;
    float* lorabf = (float*)(ws + MIDW_B);
    lorabf_gather_f32<<<2048, 256, 0, stream>>>(loraB, lorabf);
    mid_kernel<<<256, 256, 0, stream>>>(x, loraA, router, midw);
    gemm_fallback<<<2048, 256, 0, stream>>>(x, wgt, midw, lorabf, bias, out);
  }
}